// Round 4
// baseline (437.609 us; speedup 1.0000x reference)
//
#include <hip/hip_runtime.h>
#include <math.h>

// Problem constants (B,T,S,D fixed by the reference).
#define BN 8
#define TT 2048
#define SS 2048
#define DD 256
#define NSEG 128
#define SEGLEN 16   // TT / NSEG

typedef __attribute__((ext_vector_type(8))) short short8;
typedef __attribute__((ext_vector_type(4))) float floatx4;

__device__ __forceinline__ unsigned short f2bf_rne(float f) {
    unsigned int u = __float_as_uint(f);
    u = (u + 0x7FFFu + ((u >> 16) & 1u)) >> 16;
    return (unsigned short)u;
}
__device__ __forceinline__ float bf2f(unsigned short h) {
    return __uint_as_float(((unsigned int)h) << 16);
}
// Order-preserving float<->uint for atomicMax-based rowmax.
__device__ __forceinline__ unsigned int fenc(float f) {
    unsigned int b = __float_as_uint(f);
    return (b & 0x80000000u) ? ~b : (b | 0x80000000u);
}
__device__ __forceinline__ float fdec(unsigned int u) {
    return __uint_as_float((u & 0x80000000u) ? (u & 0x7FFFFFFFu) : ~u);
}

// Async global->LDS DMA, 16 B per lane.  LDS dest must be wave-uniform base
// + lane*16 (m104/m108) — all call sites below satisfy this.
__device__ __forceinline__ void async16(const unsigned short* g, unsigned short* l) {
    __builtin_amdgcn_global_load_lds(
        (const __attribute__((address_space(1))) unsigned int*)g,
        (__attribute__((address_space(3))) unsigned int*)l,
        16, 0, 0);
}

// ---------------------------------------------------------------------------
// KPREP: fused preprocessing (one launch).
//   y=0: source fp32 -> bf16 hi/lo split, row-major; zero-init rowmaxU.
//   y=1: memory_bank fp32 -> bf16 hi/lo split, row-major.
//   y=2: memory_bank -> MFMA B-fragment layout, single bf16 (old k6pre).
// All three sub-grids are 2048 blocks of 256 threads.
// ---------------------------------------------------------------------------
__global__ __launch_bounds__(256) void kprep(
    const float* __restrict__ src, const float* __restrict__ mem,
    unsigned short* __restrict__ shi, unsigned short* __restrict__ slo,
    unsigned short* __restrict__ mhirm, unsigned short* __restrict__ mlorm,
    unsigned short* __restrict__ mhi, unsigned int* __restrict__ rowmaxU)
{
    if (blockIdx.y == 2) {                    // ---- B-fragment relayout ----
        const int gid = blockIdx.x * 256 + threadIdx.x;
        const int lane = gid & 63;
        const int dt   = (gid >> 6) & 15;
        const int c    = (gid >> 10) & 63;
        const int b    = gid >> 16;
        const int quad = lane >> 4, n = lane & 15;
        const int s = c * 32 + quad * 8;
        const int d = dt * 16 + n;
        const float* srcp = mem + ((size_t)b * SS + s) * DD + d;
        short8 hi;
#pragma unroll
        for (int j = 0; j < 8; j++)
            hi[j] = (short)f2bf_rne(srcp[(size_t)j * DD]);
        *(short8*)(mhi + (size_t)gid * 8) = hi;
        return;
    }
    if (blockIdx.y == 0 && blockIdx.x < (BN * TT / 256))
        rowmaxU[blockIdx.x * 256 + threadIdx.x] = 0u;
    const float* in; unsigned short *oh, *ol;
    if (blockIdx.y == 0) { in = src; oh = shi; ol = slo; }
    else                 { in = mem; oh = mhirm; ol = mlorm; }
    const size_t base = ((size_t)blockIdx.x * 256 + threadIdx.x) * 8;
    float4 v0 = *(const float4*)(in + base);
    float4 v1 = *(const float4*)(in + base + 4);
    float f[8] = {v0.x, v0.y, v0.z, v0.w, v1.x, v1.y, v1.z, v1.w};
    short8 hv, lv;
#pragma unroll
    for (int j = 0; j < 8; j++) {
        unsigned short h = f2bf_rne(f[j]);
        hv[j] = (short)h;
        lv[j] = (short)f2bf_rne(f[j] - bf2f(h));
    }
    *(short8*)(oh + base) = hv;
    *(short8*)(ol + base) = lv;
}

// ---------------------------------------------------------------------------
// K1: align = src @ mem^T via split-bf16 MFMA (3-term), fp32 acc.
// Epilogue computes the masked per-row tile max from the acc registers
// (shfl reduce over the 16 m-lanes) and atomicMax's it into rowmaxU.
// ---------------------------------------------------------------------------
__global__ __launch_bounds__(256) void k1_mfma(
    const unsigned short* __restrict__ shi, const unsigned short* __restrict__ slo,
    const unsigned short* __restrict__ mhirm, const unsigned short* __restrict__ mlorm,
    const int* __restrict__ lens, float* __restrict__ alignb,
    unsigned int* __restrict__ rowmaxU)
{
    const int b  = blockIdx.z;
    const int len = lens[b];
    const int s0 = blockIdx.x * 128;
    if (s0 >= len) return;
    const int t0 = blockIdx.y * 128;
    const int tid = threadIdx.x;
    const int wave = tid >> 6, lane = tid & 63;
    const int wt = wave & 1, wsb = wave >> 1;
    const int quad = lane >> 4, m = lane & 15;

    __shared__ unsigned short ldsAh[128 * 32];
    __shared__ unsigned short ldsAl[128 * 32];
    __shared__ unsigned short ldsBh[128 * 32];
    __shared__ unsigned short ldsBl[128 * 32];

    const int srow = tid >> 2, sk4 = (tid & 3) * 8;
    const size_t aBase = ((size_t)(b * TT + t0 + srow)) * DD + sk4;
    const size_t bBase = ((size_t)(b * SS + s0 + srow)) * DD + sk4;
    const size_t aBase2 = aBase + (size_t)64 * DD;
    const size_t bBase2 = bBase + (size_t)64 * DD;
    const int lo1 = tid * 8, lo2 = tid * 8 + 2048;

    floatx4 acc[4][4];
#pragma unroll
    for (int i = 0; i < 4; i++)
#pragma unroll
        for (int j = 0; j < 4; j++) acc[i][j] = (floatx4)0.f;

    for (int kc = 0; kc < 8; kc++) {
        const int ko = kc * 32;
        __syncthreads();
        async16(shi   + aBase  + ko, ldsAh + lo1);
        async16(shi   + aBase2 + ko, ldsAh + lo2);
        async16(slo   + aBase  + ko, ldsAl + lo1);
        async16(slo   + aBase2 + ko, ldsAl + lo2);
        async16(mhirm + bBase  + ko, ldsBh + lo1);
        async16(mhirm + bBase2 + ko, ldsBh + lo2);
        async16(mlorm + bBase  + ko, ldsBl + lo1);
        async16(mlorm + bBase2 + ko, ldsBl + lo2);
        __syncthreads();

        short8 Ah[4], Al[4], Bh[4], Bl[4];
#pragma unroll
        for (int f = 0; f < 4; f++) {
            const int ra = (wt * 64 + f * 16 + m) * 32 + quad * 8;
            const int rb = (wsb * 64 + f * 16 + m) * 32 + quad * 8;
            Ah[f] = *(const short8*)&ldsAh[ra];
            Al[f] = *(const short8*)&ldsAl[ra];
            Bh[f] = *(const short8*)&ldsBh[rb];
            Bl[f] = *(const short8*)&ldsBl[rb];
        }
#pragma unroll
        for (int mf = 0; mf < 4; mf++)
#pragma unroll
            for (int nf = 0; nf < 4; nf++) {
                acc[mf][nf] = __builtin_amdgcn_mfma_f32_16x16x32_bf16(
                    Ah[mf], Bh[nf], acc[mf][nf], 0, 0, 0);
                acc[mf][nf] = __builtin_amdgcn_mfma_f32_16x16x32_bf16(
                    Al[mf], Bh[nf], acc[mf][nf], 0, 0, 0);
                acc[mf][nf] = __builtin_amdgcn_mfma_f32_16x16x32_bf16(
                    Ah[mf], Bl[nf], acc[mf][nf], 0, 0, 0);
            }
    }

#pragma unroll
    for (int mf = 0; mf < 4; mf++)
#pragma unroll
        for (int reg = 0; reg < 4; reg++) {
            const int t = t0 + wt * 64 + mf * 16 + quad * 4 + reg;
            float* row = alignb + ((size_t)(b * TT + t)) * SS + s0 + wsb * 64 + m;
#pragma unroll
            for (int nf = 0; nf < 4; nf++)
                row[nf * 16] = acc[mf][nf][reg];
        }

    // Epilogue 2: masked per-row max of this tile-half -> atomicMax.
    if (s0 + wsb * 64 < len) {
#pragma unroll
        for (int mf = 0; mf < 4; mf++)
#pragma unroll
            for (int reg = 0; reg < 4; reg++) {
                float mx = -INFINITY;
#pragma unroll
                for (int nf = 0; nf < 4; nf++) {
                    const int col = s0 + wsb * 64 + nf * 16 + m;
                    mx = (col < len) ? fmaxf(mx, acc[mf][nf][reg]) : mx;
                }
#pragma unroll
                for (int off = 1; off < 16; off <<= 1)       // reduce over m-lanes
                    mx = fmaxf(mx, __shfl_xor(mx, off, 64));
                if (m == 0) {
                    const int t = t0 + wt * 64 + mf * 16 + quad * 4 + reg;
                    atomicMax(&rowmaxU[b * TT + t], fenc(mx));
                }
            }
    }
}

// ---------------------------------------------------------------------------
// K3: per-(b,seg,s) sum over the segment's 16 rows of e = exp(align - max).
// float4-vectorized: 4 s-columns per thread, 4-row unroll for MLP.
// ---------------------------------------------------------------------------
__global__ __launch_bounds__(256) void k3_segsum(
    const float* __restrict__ alignb, const unsigned int* __restrict__ rowmaxU,
    const int* __restrict__ lens, float* __restrict__ segsum)
{
    const int b = blockIdx.z, seg = blockIdx.y;
    const int s4 = (blockIdx.x * 256 + threadIdx.x) * 4;
    const int len = lens[b];
    float4 sum = {0.f, 0.f, 0.f, 0.f};
    if (s4 < len) {
        const float* base = alignb + ((size_t)b * TT + seg * SEGLEN) * SS + s4;
        const unsigned int* rmu = rowmaxU + b * TT + seg * SEGLEN;
        const bool v1 = (s4 + 1) < len, v2 = (s4 + 2) < len, v3 = (s4 + 3) < len;
#pragma unroll 4
        for (int r = 0; r < SEGLEN; r++) {
            const float m = fdec(rmu[r]);
            float4 v = *(const float4*)(base + (size_t)r * SS);
            sum.x += __expf(v.x - m);
            sum.y += v1 ? __expf(v.y - m) : 0.f;
            sum.z += v2 ? __expf(v.z - m) : 0.f;
            sum.w += v3 ? __expf(v.w - m) : 0.f;
        }
    }
    *(float4*)(segsum + ((size_t)b * NSEG + seg) * SS + s4) = sum;
}

// ---------------------------------------------------------------------------
// K4: exclusive prefix over the 128 segments, per (b,s) column, in place.
// ---------------------------------------------------------------------------
__global__ __launch_bounds__(256) void k4_prefix(float* __restrict__ segsum)
{
    const int b = blockIdx.y;
    const int s = blockIdx.x * 256 + threadIdx.x;
    float run = 0.f;
    for (int g = 0; g < NSEG / 8; g++) {
        float v[8];
#pragma unroll
        for (int i = 0; i < 8; i++)
            v[i] = segsum[((size_t)b * NSEG + g * 8 + i) * SS + s];
#pragma unroll
        for (int i = 0; i < 8; i++) {
            segsum[((size_t)b * NSEG + g * 8 + i) * SS + s] = run;
            run += v[i];
        }
    }
}

// ---------------------------------------------------------------------------
// K5: full-row scan + normalize, 16 t-rows per block (NSEG=128 -> 1024
// blocks, ~4 blocks/CU).  No big LDS tile; writes the FINAL normalized
// align_vectors in place.  Cols >= len get 0.
// ---------------------------------------------------------------------------
__global__ __launch_bounds__(256) void k5_scan(
    float* __restrict__ alignb, const unsigned int* __restrict__ rowmaxU,
    const float* __restrict__ segsum, const int* __restrict__ lens)
{
    const int seg = blockIdx.x, b = blockIdx.y;
    const int len = lens[b];
    const int c0 = threadIdx.x * 8;
    const int lane = threadIdx.x & 63, wid = threadIdx.x >> 6;
    const bool anyv = c0 < len;

    __shared__ float red[8];

    float psum[8];
    {
        const float* sp = segsum + ((size_t)b * NSEG + seg) * SS + c0;
        float4 a = *(const float4*)sp, c = *(const float4*)(sp + 4);
        psum[0] = a.x; psum[1] = a.y; psum[2] = a.z; psum[3] = a.w;
        psum[4] = c.x; psum[5] = c.y; psum[6] = c.z; psum[7] = c.w;
    }

    float* rowp = alignb + ((size_t)(b * TT + seg * SEGLEN)) * SS + c0;

    float avn[8] = {0.f, 0.f, 0.f, 0.f, 0.f, 0.f, 0.f, 0.f};
    if (anyv) {
        float4 a = *(const float4*)rowp, c = *(const float4*)(rowp + 4);
        avn[0] = a.x; avn[1] = a.y; avn[2] = a.z; avn[3] = a.w;
        avn[4] = c.x; avn[5] = c.y; avn[6] = c.z; avn[7] = c.w;
    }

    for (int r = 0; r < SEGLEN; r++) {
        const int t = seg * SEGLEN + r;
        const float m = fdec(rowmaxU[b * TT + t]);
        float av[8];
#pragma unroll
        for (int j = 0; j < 8; j++) av[j] = avn[j];
        if (anyv && r + 1 < SEGLEN) {          // prefetch next row
            const float* np = rowp + (size_t)(r + 1) * SS;
            float4 a = *(const float4*)np, c = *(const float4*)(np + 4);
            avn[0] = a.x; avn[1] = a.y; avn[2] = a.z; avn[3] = a.w;
            avn[4] = c.x; avn[5] = c.y; avn[6] = c.z; avn[7] = c.w;
        }
        float u[8], rsum = 0.f;
#pragma unroll
        for (int j = 0; j < 8; j++) {
            float e = (c0 + j < len) ? __expf(av[j] - m) : 0.f;
            float div = (t == 0) ? 1.0f : (psum[j] + 1e-20f);
            u[j] = e * __builtin_amdgcn_rcpf(div);
            psum[j] += e;
            rsum += u[j];
        }
#pragma unroll
        for (int off = 32; off > 0; off >>= 1)
            rsum += __shfl_down(rsum, off, 64);
        const int pp = (r & 1) * 4;
        if (lane == 0) red[pp + wid] = rsum;
        __syncthreads();
        const float inv = 1.0f / (red[pp] + red[pp + 1] + red[pp + 2] + red[pp + 3]);
        float* wp = rowp + (size_t)r * SS;
        float4 o0 = {u[0] * inv, u[1] * inv, u[2] * inv, u[3] * inv};
        float4 o1 = {u[4] * inv, u[5] * inv, u[6] * inv, u[7] * inv};
        *(float4*)wp = o0;
        *(float4*)(wp + 4) = o1;
    }
}

// ---------------------------------------------------------------------------
// K67: context GEMM + output projection fused.  Block (b, 32-t-row tile):
// Phase 1 (verified k6 body): c-tile via single-bf16 MFMA over full valid s,
// results kept in acc regs -> staged to 32 KB LDS cT (no 17 MB cfull
// round-trip).  Phase 2 (verified k7 body): attn = tanh([c,src] @ W_out)
// with the cfull read replaced by cT.
// ---------------------------------------------------------------------------
__global__ __launch_bounds__(256) void k67_ctx_out(
    const float* __restrict__ alignb, const unsigned short* __restrict__ mhi,
    const int* __restrict__ lens, const float* __restrict__ src,
    const float* __restrict__ W, float* __restrict__ attn)
{
    const int b  = blockIdx.x;
    const int t0 = blockIdx.y * 32;
    const int tid  = threadIdx.x;
    const int wave = tid >> 6, lane = tid & 63;
    const int quad = lane >> 4, m = lane & 15;

    __shared__ __align__(16) float cT[32][256];     // 32 KB
    __shared__ __align__(16) float wT[32][256];     // 32 KB
    __shared__ float xT[32][32];                    //  4 KB

    // ---- Phase 1: context GEMM (k6 body) ----
    const int len = lens[b];
    int cmax = (len + 31) >> 5;
    if (cmax > 64) cmax = 64;

    floatx4 acc[2][4];
#pragma unroll
    for (int i = 0; i < 2; i++)
#pragma unroll
        for (int j = 0; j < 4; j++) acc[i][j] = (floatx4)0.f;

    const float* aBase = alignb + ((size_t)(b * TT + t0 + m)) * SS + quad * 8;

    for (int c = 0; c < cmax; c++) {
        short8 Bf[4];
#pragma unroll
        for (int j = 0; j < 4; j++) {
            const int dt = wave * 4 + j;
            Bf[j] = *(const short8*)(mhi +
                (((size_t)(b * 64 + c) * 16 + dt) * 64 + lane) * 8);
        }
#pragma unroll
        for (int mf = 0; mf < 2; mf++) {
            const float* ap = aBase + (size_t)(mf * 16) * SS + c * 32;
            float4 v0 = *(const float4*)ap;
            float4 v1 = *(const float4*)(ap + 4);
            union { short8 s; unsigned int u[4]; } pk;   // bf16 RTZ pack
            pk.u[0] = (__float_as_uint(v0.x) >> 16) | (__float_as_uint(v0.y) & 0xFFFF0000u);
            pk.u[1] = (__float_as_uint(v0.z) >> 16) | (__float_as_uint(v0.w) & 0xFFFF0000u);
            pk.u[2] = (__float_as_uint(v1.x) >> 16) | (__float_as_uint(v1.y) & 0xFFFF0000u);
            pk.u[3] = (__float_as_uint(v1.z) >> 16) | (__float_as_uint(v1.w) & 0xFFFF0000u);
#pragma unroll
            for (int j = 0; j < 4; j++)
                acc[mf][j] = __builtin_amdgcn_mfma_f32_16x16x32_bf16(
                    pk.s, Bf[j], acc[mf][j], 0, 0, 0);
        }
    }

#pragma unroll
    for (int mf = 0; mf < 2; mf++)
#pragma unroll
        for (int j = 0; j < 4; j++) {
            const int d = wave * 64 + j * 16 + m;
#pragma unroll
            for (int reg = 0; reg < 4; reg++)
                cT[mf * 16 + quad * 4 + reg][d] = acc[mf][j][reg];
        }
    // (visibility of cT is guaranteed by the barrier at the top of the k0 loop)

    // ---- Phase 2: output projection (k7 body, cfull -> cT) ----
    const int tx = tid & 63, ty = tid >> 6;

    float4 oacc[8];
#pragma unroll
    for (int i = 0; i < 8; i++) oacc[i] = make_float4(0.f, 0.f, 0.f, 0.f);

    for (int k0 = 0; k0 < 2 * DD; k0 += 32) {
        __syncthreads();
#pragma unroll
        for (int it = 0; it < 8; it++) {
            int f = tid + it * 256;
            int kr = f >> 6, col = (f & 63) * 4;
            *(float4*)&wT[kr][col] =
                *(const float4*)(W + (size_t)(k0 + kr) * DD + col);
        }
#pragma unroll
        for (int rep = 0; rep < 4; rep++) {
            int idx = tid + rep * 256;
            int r = idx >> 5, c = idx & 31;
            int k = k0 + c;
            float x;
            if (k < DD) {
                x = cT[r][k];
            } else {
                x = src[((size_t)b * TT + t0 + r) * DD + (k - DD)];
            }
            xT[r][c] = x;
        }
        __syncthreads();
#pragma unroll
        for (int kk = 0; kk < 32; kk++) {
            float4 w4 = *(const float4*)&wT[kk][tx * 4];
#pragma unroll
            for (int r4 = 0; r4 < 8; r4++) {
                float x = xT[ty + r4 * 4][kk];
                oacc[r4].x += x * w4.x; oacc[r4].y += x * w4.y;
                oacc[r4].z += x * w4.z; oacc[r4].w += x * w4.w;
            }
        }
    }
#pragma unroll
    for (int r4 = 0; r4 < 8; r4++) {
        const int t = t0 + ty + r4 * 4;
        float4 o;
        o.x = tanhf(oacc[r4].x); o.y = tanhf(oacc[r4].y);
        o.z = tanhf(oacc[r4].z); o.w = tanhf(oacc[r4].w);
        *(float4*)(attn + ((size_t)b * TT + t) * DD + tx * 4) = o;
    }
}

// ---------------------------------------------------------------------------
extern "C" void kernel_launch(void* const* d_in, const int* in_sizes, int n_in,
                              void* d_out, int out_size, void* d_ws, size_t ws_size,
                              hipStream_t stream)
{
    const float* src  = (const float*)d_in[0];   // [B,T,D]
    const float* mem  = (const float*)d_in[1];   // [B,S,D]
    const float* Wout = (const float*)d_in[2];   // [2D,D]
    const int*   lens = (const int*)d_in[3];     // [B]

    float* out    = (float*)d_out;
    float* attn   = out;                               // [B,T,D]
    float* alignb = out + (size_t)BN * TT * DD;        // [B,T,S] scratch -> final

    unsigned int* rowmaxU = (unsigned int*)d_ws;                       // 64 KB
    float* segsum = (float*)(rowmaxU + (size_t)BN * TT);               // 8 MB
    unsigned short* mhi = (unsigned short*)(segsum + (size_t)BN * NSEG * SS); // 8 MB
    unsigned short* shi   = mhi + (size_t)BN * SS * DD;                // 8 MB (dead after k1)
    unsigned short* slo   = shi + (size_t)BN * TT * DD;                // 8 MB (dead after k1)
    unsigned short* mhirm = slo + (size_t)BN * TT * DD;                // 8 MB (dead after k1)
    unsigned short* mlorm = mhirm + (size_t)BN * SS * DD;              // 8 MB (dead after k1)

    kprep<<<dim3(BN * TT * DD / (256 * 8), 3), 256, 0, stream>>>(
        src, mem, shi, slo, mhirm, mlorm, mhi, rowmaxU);
    k1_mfma<<<dim3(SS / 128, TT / 128, BN), 256, 0, stream>>>(
        shi, slo, mhirm, mlorm, lens, alignb, rowmaxU);
    k3_segsum<<<dim3(SS / 1024, NSEG, BN), 256, 0, stream>>>(alignb, rowmaxU, lens, segsum);
    k4_prefix<<<dim3(SS / 256, BN), 256, 0, stream>>>(segsum);
    k5_scan<<<dim3(NSEG, BN), 256, 0, stream>>>(alignb, rowmaxU, segsum, lens);
    k67_ctx_out<<<dim3(BN, TT / 32), 256, 0, stream>>>(
        alignb, mhi, lens, src, Wout, attn);
}

// Round 6
// 423.037 us; speedup vs baseline: 1.0344x; 1.0344x over previous
//
#include <hip/hip_runtime.h>
#include <math.h>

// Problem constants (B,T,S,D fixed by the reference).
#define BN 8
#define TT 2048
#define SS 2048
#define DD 256
#define NSEG 128
#define SEGLEN 16   // TT / NSEG

typedef __attribute__((ext_vector_type(8))) short short8;
typedef __attribute__((ext_vector_type(4))) float floatx4;

__device__ __forceinline__ unsigned short f2bf_rne(float f) {
    unsigned int u = __float_as_uint(f);
    u = (u + 0x7FFFu + ((u >> 16) & 1u)) >> 16;
    return (unsigned short)u;
}
__device__ __forceinline__ float bf2f(unsigned short h) {
    return __uint_as_float(((unsigned int)h) << 16);
}
// Order-preserving float<->uint for atomicMax-based rowmax.
__device__ __forceinline__ unsigned int fenc(float f) {
    unsigned int b = __float_as_uint(f);
    return (b & 0x80000000u) ? ~b : (b | 0x80000000u);
}
__device__ __forceinline__ float fdec(unsigned int u) {
    return __uint_as_float((u & 0x80000000u) ? (u & 0x7FFFFFFFu) : ~u);
}

// Async global->LDS DMA, 16 B per lane.  LDS dest must be wave-uniform base
// + lane*16 (m104/m108) — all call sites below satisfy this.
__device__ __forceinline__ void async16(const unsigned short* g, unsigned short* l) {
    __builtin_amdgcn_global_load_lds(
        (const __attribute__((address_space(1))) unsigned int*)g,
        (__attribute__((address_space(3))) unsigned int*)l,
        16, 0, 0);
}

// ---------------------------------------------------------------------------
// KPREP: fused preprocessing (one launch).
//   y=0: source fp32 -> bf16 hi/lo split, row-major; zero-init rowmaxU.
//   y=1: memory_bank fp32 -> bf16 hi/lo split, row-major.
//   y=2: memory_bank -> MFMA B-fragment layout, single bf16 (old k6pre).
// All three sub-grids are 2048 blocks of 256 threads.
// ---------------------------------------------------------------------------
__global__ __launch_bounds__(256) void kprep(
    const float* __restrict__ src, const float* __restrict__ mem,
    unsigned short* __restrict__ shi, unsigned short* __restrict__ slo,
    unsigned short* __restrict__ mhirm, unsigned short* __restrict__ mlorm,
    unsigned short* __restrict__ mhi, unsigned int* __restrict__ rowmaxU)
{
    if (blockIdx.y == 2) {                    // ---- B-fragment relayout ----
        const int gid = blockIdx.x * 256 + threadIdx.x;
        const int lane = gid & 63;
        const int dt   = (gid >> 6) & 15;
        const int c    = (gid >> 10) & 63;
        const int b    = gid >> 16;
        const int quad = lane >> 4, n = lane & 15;
        const int s = c * 32 + quad * 8;
        const int d = dt * 16 + n;
        const float* srcp = mem + ((size_t)b * SS + s) * DD + d;
        short8 hi;
#pragma unroll
        for (int j = 0; j < 8; j++)
            hi[j] = (short)f2bf_rne(srcp[(size_t)j * DD]);
        *(short8*)(mhi + (size_t)gid * 8) = hi;
        return;
    }
    if (blockIdx.y == 0 && blockIdx.x < (BN * TT / 256))
        rowmaxU[blockIdx.x * 256 + threadIdx.x] = 0u;
    const float* in; unsigned short *oh, *ol;
    if (blockIdx.y == 0) { in = src; oh = shi; ol = slo; }
    else                 { in = mem; oh = mhirm; ol = mlorm; }
    const size_t base = ((size_t)blockIdx.x * 256 + threadIdx.x) * 8;
    float4 v0 = *(const float4*)(in + base);
    float4 v1 = *(const float4*)(in + base + 4);
    float f[8] = {v0.x, v0.y, v0.z, v0.w, v1.x, v1.y, v1.z, v1.w};
    short8 hv, lv;
#pragma unroll
    for (int j = 0; j < 8; j++) {
        unsigned short h = f2bf_rne(f[j]);
        hv[j] = (short)h;
        lv[j] = (short)f2bf_rne(f[j] - bf2f(h));
    }
    *(short8*)(oh + base) = hv;
    *(short8*)(ol + base) = lv;
}

// ---------------------------------------------------------------------------
// K1: align = src @ mem^T via split-bf16 MFMA (3-term), fp32 acc.
// Epilogue computes the masked per-row tile max from the acc registers
// (shfl reduce over the 16 m-lanes) and atomicMax's it into rowmaxU.
// ---------------------------------------------------------------------------
__global__ __launch_bounds__(256) void k1_mfma(
    const unsigned short* __restrict__ shi, const unsigned short* __restrict__ slo,
    const unsigned short* __restrict__ mhirm, const unsigned short* __restrict__ mlorm,
    const int* __restrict__ lens, float* __restrict__ alignb,
    unsigned int* __restrict__ rowmaxU)
{
    const int b  = blockIdx.z;
    const int len = lens[b];
    const int s0 = blockIdx.x * 128;
    if (s0 >= len) return;
    const int t0 = blockIdx.y * 128;
    const int tid = threadIdx.x;
    const int wave = tid >> 6, lane = tid & 63;
    const int wt = wave & 1, wsb = wave >> 1;
    const int quad = lane >> 4, m = lane & 15;

    __shared__ unsigned short ldsAh[128 * 32];
    __shared__ unsigned short ldsAl[128 * 32];
    __shared__ unsigned short ldsBh[128 * 32];
    __shared__ unsigned short ldsBl[128 * 32];

    const int srow = tid >> 2, sk4 = (tid & 3) * 8;
    const size_t aBase = ((size_t)(b * TT + t0 + srow)) * DD + sk4;
    const size_t bBase = ((size_t)(b * SS + s0 + srow)) * DD + sk4;
    const size_t aBase2 = aBase + (size_t)64 * DD;
    const size_t bBase2 = bBase + (size_t)64 * DD;
    const int lo1 = tid * 8, lo2 = tid * 8 + 2048;

    floatx4 acc[4][4];
#pragma unroll
    for (int i = 0; i < 4; i++)
#pragma unroll
        for (int j = 0; j < 4; j++) acc[i][j] = (floatx4)0.f;

    for (int kc = 0; kc < 8; kc++) {
        const int ko = kc * 32;
        __syncthreads();
        async16(shi   + aBase  + ko, ldsAh + lo1);
        async16(shi   + aBase2 + ko, ldsAh + lo2);
        async16(slo   + aBase  + ko, ldsAl + lo1);
        async16(slo   + aBase2 + ko, ldsAl + lo2);
        async16(mhirm + bBase  + ko, ldsBh + lo1);
        async16(mhirm + bBase2 + ko, ldsBh + lo2);
        async16(mlorm + bBase  + ko, ldsBl + lo1);
        async16(mlorm + bBase2 + ko, ldsBl + lo2);
        __syncthreads();

        short8 Ah[4], Al[4], Bh[4], Bl[4];
#pragma unroll
        for (int f = 0; f < 4; f++) {
            const int ra = (wt * 64 + f * 16 + m) * 32 + quad * 8;
            const int rb = (wsb * 64 + f * 16 + m) * 32 + quad * 8;
            Ah[f] = *(const short8*)&ldsAh[ra];
            Al[f] = *(const short8*)&ldsAl[ra];
            Bh[f] = *(const short8*)&ldsBh[rb];
            Bl[f] = *(const short8*)&ldsBl[rb];
        }
#pragma unroll
        for (int mf = 0; mf < 4; mf++)
#pragma unroll
            for (int nf = 0; nf < 4; nf++) {
                acc[mf][nf] = __builtin_amdgcn_mfma_f32_16x16x32_bf16(
                    Ah[mf], Bh[nf], acc[mf][nf], 0, 0, 0);
                acc[mf][nf] = __builtin_amdgcn_mfma_f32_16x16x32_bf16(
                    Al[mf], Bh[nf], acc[mf][nf], 0, 0, 0);
                acc[mf][nf] = __builtin_amdgcn_mfma_f32_16x16x32_bf16(
                    Ah[mf], Bl[nf], acc[mf][nf], 0, 0, 0);
            }
    }

#pragma unroll
    for (int mf = 0; mf < 4; mf++)
#pragma unroll
        for (int reg = 0; reg < 4; reg++) {
            const int t = t0 + wt * 64 + mf * 16 + quad * 4 + reg;
            float* row = alignb + ((size_t)(b * TT + t)) * SS + s0 + wsb * 64 + m;
#pragma unroll
            for (int nf = 0; nf < 4; nf++)
                row[nf * 16] = acc[mf][nf][reg];
        }

    // Epilogue 2: masked per-row max of this tile-half -> atomicMax.
    if (s0 + wsb * 64 < len) {
#pragma unroll
        for (int mf = 0; mf < 4; mf++)
#pragma unroll
            for (int reg = 0; reg < 4; reg++) {
                float mx = -INFINITY;
#pragma unroll
                for (int nf = 0; nf < 4; nf++) {
                    const int col = s0 + wsb * 64 + nf * 16 + m;
                    mx = (col < len) ? fmaxf(mx, acc[mf][nf][reg]) : mx;
                }
#pragma unroll
                for (int off = 1; off < 16; off <<= 1)       // reduce over m-lanes
                    mx = fmaxf(mx, __shfl_xor(mx, off, 64));
                if (m == 0) {
                    const int t = t0 + wt * 64 + mf * 16 + quad * 4 + reg;
                    atomicMax(&rowmaxU[b * TT + t], fenc(mx));
                }
            }
    }
}

// ---------------------------------------------------------------------------
// K3: per-(b,seg,s) sum over the segment's 16 rows of e = exp(align - max).
// float4-vectorized: 4 s-columns per thread, 4-row unroll for MLP.
// ---------------------------------------------------------------------------
__global__ __launch_bounds__(256) void k3_segsum(
    const float* __restrict__ alignb, const unsigned int* __restrict__ rowmaxU,
    const int* __restrict__ lens, float* __restrict__ segsum)
{
    const int b = blockIdx.z, seg = blockIdx.y;
    const int s4 = (blockIdx.x * 256 + threadIdx.x) * 4;
    const int len = lens[b];
    float4 sum = {0.f, 0.f, 0.f, 0.f};
    if (s4 < len) {
        const float* base = alignb + ((size_t)b * TT + seg * SEGLEN) * SS + s4;
        const unsigned int* rmu = rowmaxU + b * TT + seg * SEGLEN;
        const bool v1 = (s4 + 1) < len, v2 = (s4 + 2) < len, v3 = (s4 + 3) < len;
#pragma unroll 4
        for (int r = 0; r < SEGLEN; r++) {
            const float m = fdec(rmu[r]);
            float4 v = *(const float4*)(base + (size_t)r * SS);
            sum.x += __expf(v.x - m);
            sum.y += v1 ? __expf(v.y - m) : 0.f;
            sum.z += v2 ? __expf(v.z - m) : 0.f;
            sum.w += v3 ? __expf(v.w - m) : 0.f;
        }
    }
    *(float4*)(segsum + ((size_t)b * NSEG + seg) * SS + s4) = sum;
}

// ---------------------------------------------------------------------------
// K4: exclusive prefix over the 128 segments, per (b,s) column, in place.
// ---------------------------------------------------------------------------
__global__ __launch_bounds__(256) void k4_prefix(float* __restrict__ segsum)
{
    const int b = blockIdx.y;
    const int s = blockIdx.x * 256 + threadIdx.x;
    float run = 0.f;
    for (int g = 0; g < NSEG / 8; g++) {
        float v[8];
#pragma unroll
        for (int i = 0; i < 8; i++)
            v[i] = segsum[((size_t)b * NSEG + g * 8 + i) * SS + s];
#pragma unroll
        for (int i = 0; i < 8; i++) {
            segsum[((size_t)b * NSEG + g * 8 + i) * SS + s] = run;
            run += v[i];
        }
    }
}

// ---------------------------------------------------------------------------
// K5: full-row scan + normalize, 16 t-rows per block (NSEG=128 -> 1024
// blocks, ~4 blocks/CU).  No big LDS tile; writes the FINAL normalized
// align_vectors in place.  Cols >= len get 0.
// ---------------------------------------------------------------------------
__global__ __launch_bounds__(256) void k5_scan(
    float* __restrict__ alignb, const unsigned int* __restrict__ rowmaxU,
    const float* __restrict__ segsum, const int* __restrict__ lens)
{
    const int seg = blockIdx.x, b = blockIdx.y;
    const int len = lens[b];
    const int c0 = threadIdx.x * 8;
    const int lane = threadIdx.x & 63, wid = threadIdx.x >> 6;
    const bool anyv = c0 < len;

    __shared__ float red[8];

    float psum[8];
    {
        const float* sp = segsum + ((size_t)b * NSEG + seg) * SS + c0;
        float4 a = *(const float4*)sp, c = *(const float4*)(sp + 4);
        psum[0] = a.x; psum[1] = a.y; psum[2] = a.z; psum[3] = a.w;
        psum[4] = c.x; psum[5] = c.y; psum[6] = c.z; psum[7] = c.w;
    }

    float* rowp = alignb + ((size_t)(b * TT + seg * SEGLEN)) * SS + c0;

    float avn[8] = {0.f, 0.f, 0.f, 0.f, 0.f, 0.f, 0.f, 0.f};
    if (anyv) {
        float4 a = *(const float4*)rowp, c = *(const float4*)(rowp + 4);
        avn[0] = a.x; avn[1] = a.y; avn[2] = a.z; avn[3] = a.w;
        avn[4] = c.x; avn[5] = c.y; avn[6] = c.z; avn[7] = c.w;
    }

    for (int r = 0; r < SEGLEN; r++) {
        const int t = seg * SEGLEN + r;
        const float m = fdec(rowmaxU[b * TT + t]);
        float av[8];
#pragma unroll
        for (int j = 0; j < 8; j++) av[j] = avn[j];
        if (anyv && r + 1 < SEGLEN) {          // prefetch next row
            const float* np = rowp + (size_t)(r + 1) * SS;
            float4 a = *(const float4*)np, c = *(const float4*)(np + 4);
            avn[0] = a.x; avn[1] = a.y; avn[2] = a.z; avn[3] = a.w;
            avn[4] = c.x; avn[5] = c.y; avn[6] = c.z; avn[7] = c.w;
        }
        float u[8], rsum = 0.f;
#pragma unroll
        for (int j = 0; j < 8; j++) {
            float e = (c0 + j < len) ? __expf(av[j] - m) : 0.f;
            float div = (t == 0) ? 1.0f : (psum[j] + 1e-20f);
            u[j] = e * __builtin_amdgcn_rcpf(div);
            psum[j] += e;
            rsum += u[j];
        }
#pragma unroll
        for (int off = 32; off > 0; off >>= 1)
            rsum += __shfl_down(rsum, off, 64);
        const int pp = (r & 1) * 4;
        if (lane == 0) red[pp + wid] = rsum;
        __syncthreads();
        const float inv = 1.0f / (red[pp] + red[pp + 1] + red[pp + 2] + red[pp + 3]);
        float* wp = rowp + (size_t)r * SS;
        float4 o0 = {u[0] * inv, u[1] * inv, u[2] * inv, u[3] * inv};
        float4 o1 = {u[4] * inv, u[5] * inv, u[6] * inv, u[7] * inv};
        *(float4*)wp = o0;
        *(float4*)(wp + 4) = o1;
    }
}

// ---------------------------------------------------------------------------
// K6: c = align_vectors @ mem, single-bf16 MFMA.  Block (b, 16 t-rows) ->
// 1024 blocks, 8 KB LDS, launch_bounds(256,4) -> 4 blocks/CU, 16 waves/CU.
// The A-operand (normalized align rows) is staged into LDS via coalesced
// global_load_lds with PRE-SWIZZLED global source (flat ^ ((row&7)<<4),
// involution; LDS dest stays linear per the wave-uniform constraint), then
// read as ds_read_b128 fragments at the same XOR -> bank-balanced.
// k1's verified 2-barrier chunk loop; cols >= len are zero after k5.
// ---------------------------------------------------------------------------
__global__ __launch_bounds__(256, 4) void k6_context(
    const float* __restrict__ alignb, const unsigned short* __restrict__ mhi,
    const int* __restrict__ lens, float* __restrict__ cfull)
{
    const int b  = blockIdx.x;
    const int t0 = blockIdx.y * 16;
    const int tid  = threadIdx.x;
    const int wave = tid >> 6, lane = tid & 63;
    const int quad = lane >> 4, m = lane & 15;

    const int len = lens[b];
    int nch = (len + 127) >> 7;            // 128-col chunks of s
    if (nch > 16) nch = 16;

    __shared__ __align__(16) unsigned char ldsA[16 * 512];   // [16 rows][512 B]

    floatx4 acc[4];
#pragma unroll
    for (int j = 0; j < 4; j++) acc[j] = (floatx4)0.f;

    const char* aRow0 = (const char*)(alignb + ((size_t)(b * TT + t0)) * SS);

    // Stage addresses: 2 issues x 4 KB; flat = i*4096 + tid*16, row = flat>>9.
    const int flat0 = tid * 16;
    const int flat1 = 4096 + tid * 16;
    const int row0 = flat0 >> 9, row1 = flat1 >> 9;
    const int col0 = (flat0 ^ ((row0 & 7) << 4)) & 511;   // pre-swizzled src col
    const int col1 = (flat1 ^ ((row1 & 7) << 4)) & 511;
    const char* src0 = aRow0 + (size_t)row0 * (SS * 4) + col0;
    const char* src1 = aRow0 + (size_t)row1 * (SS * 4) + col1;

    for (int cc = 0; cc < nch; cc++) {
        __syncthreads();                     // previous chunk's reads done
        async16((const unsigned short*)(src0 + cc * 512),
                (unsigned short*)(ldsA + flat0));
        async16((const unsigned short*)(src1 + cc * 512),
                (unsigned short*)(ldsA + flat1));
        __syncthreads();                     // drains vmcnt(0) then barrier

#pragma unroll
        for (int c4 = 0; c4 < 4; c4++) {
            const int c = cc * 4 + c4;
            short8 Bf[4];
#pragma unroll
            for (int j = 0; j < 4; j++) {
                const int dt = wave * 4 + j;
                Bf[j] = *(const short8*)(mhi +
                    (((size_t)(b * 64 + c) * 16 + dt) * 64 + lane) * 8);
            }
            const int lb = (m * 512 + c4 * 128 + quad * 32) ^ ((m & 7) << 4);
            float4 v0 = *(const float4*)(ldsA + lb);
            float4 v1 = *(const float4*)(ldsA + (lb ^ 16));
            union { short8 s; unsigned int u[4]; } pk;   // bf16 RTZ pack
            pk.u[0] = (__float_as_uint(v0.x) >> 16) | (__float_as_uint(v0.y) & 0xFFFF0000u);
            pk.u[1] = (__float_as_uint(v0.z) >> 16) | (__float_as_uint(v0.w) & 0xFFFF0000u);
            pk.u[2] = (__float_as_uint(v1.x) >> 16) | (__float_as_uint(v1.y) & 0xFFFF0000u);
            pk.u[3] = (__float_as_uint(v1.z) >> 16) | (__float_as_uint(v1.w) & 0xFFFF0000u);
#pragma unroll
            for (int j = 0; j < 4; j++)
                acc[j] = __builtin_amdgcn_mfma_f32_16x16x32_bf16(
                    pk.s, Bf[j], acc[j], 0, 0, 0);
        }
    }

#pragma unroll
    for (int j = 0; j < 4; j++) {
        const int d = wave * 64 + j * 16 + m;
#pragma unroll
        for (int reg = 0; reg < 4; reg++) {
            const int t = t0 + quad * 4 + reg;
            cfull[((size_t)(b * TT + t)) * DD + d] = acc[j][reg];
        }
    }
}

// ---------------------------------------------------------------------------
// K7: attn_h = tanh([c, source] @ W_out); c is complete (no partials).
// ---------------------------------------------------------------------------
__global__ __launch_bounds__(256) void k7_out(
    const float* __restrict__ cfull, const float* __restrict__ src,
    const float* __restrict__ W, float* __restrict__ attn)
{
    const int b = blockIdx.y;
    const int t0 = blockIdx.x * 32;
    const int tid = threadIdx.x;
    const int tx = tid & 63, ty = tid >> 6;

    __shared__ __align__(16) float wT[32][256];
    __shared__ float xT[32][32];

    float4 acc[8];
#pragma unroll
    for (int i = 0; i < 8; i++) acc[i] = make_float4(0.f, 0.f, 0.f, 0.f);

    for (int k0 = 0; k0 < 2 * DD; k0 += 32) {
        __syncthreads();
#pragma unroll
        for (int it = 0; it < 8; it++) {
            int f = tid + it * 256;
            int kr = f >> 6, col = (f & 63) * 4;
            *(float4*)&wT[kr][col] =
                *(const float4*)(W + (size_t)(k0 + kr) * DD + col);
        }
#pragma unroll
        for (int rep = 0; rep < 4; rep++) {
            int idx = tid + rep * 256;
            int r = idx >> 5, c = idx & 31;
            int k = k0 + c;
            float x;
            if (k < DD) {
                x = cfull[((size_t)b * TT + t0 + r) * DD + k];
            } else {
                x = src[((size_t)b * TT + t0 + r) * DD + (k - DD)];
            }
            xT[r][c] = x;
        }
        __syncthreads();
#pragma unroll
        for (int kk = 0; kk < 32; kk++) {
            float4 w4 = *(const float4*)&wT[kk][tx * 4];
#pragma unroll
            for (int r4 = 0; r4 < 8; r4++) {
                float x = xT[ty + r4 * 4][kk];
                acc[r4].x += x * w4.x; acc[r4].y += x * w4.y;
                acc[r4].z += x * w4.z; acc[r4].w += x * w4.w;
            }
        }
    }
#pragma unroll
    for (int r4 = 0; r4 < 8; r4++) {
        const int t = t0 + ty + r4 * 4;
        float4 o;
        o.x = tanhf(acc[r4].x); o.y = tanhf(acc[r4].y);
        o.z = tanhf(acc[r4].z); o.w = tanhf(acc[r4].w);
        *(float4*)(attn + ((size_t)b * TT + t) * DD + tx * 4) = o;
    }
}

// ---------------------------------------------------------------------------
extern "C" void kernel_launch(void* const* d_in, const int* in_sizes, int n_in,
                              void* d_out, int out_size, void* d_ws, size_t ws_size,
                              hipStream_t stream)
{
    const float* src  = (const float*)d_in[0];   // [B,T,D]
    const float* mem  = (const float*)d_in[1];   // [B,S,D]
    const float* Wout = (const float*)d_in[2];   // [2D,D]
    const int*   lens = (const int*)d_in[3];     // [B]

    float* out    = (float*)d_out;
    float* attn   = out;                               // [B,T,D]
    float* alignb = out + (size_t)BN * TT * DD;        // [B,T,S] scratch -> final

    unsigned int* rowmaxU = (unsigned int*)d_ws;                       // 64 KB
    float* segsum = (float*)(rowmaxU + (size_t)BN * TT);               // 8 MB
    unsigned short* mhi = (unsigned short*)(segsum + (size_t)BN * NSEG * SS); // 8 MB
    unsigned short* shi   = mhi + (size_t)BN * SS * DD;                // 8 MB (dead after k1)
    unsigned short* slo   = shi + (size_t)BN * TT * DD;                // 8 MB (dead after k1)
    unsigned short* mhirm = slo + (size_t)BN * TT * DD;                // 8 MB (dead after k1)
    unsigned short* mlorm = mhirm + (size_t)BN * SS * DD;              // 8 MB (dead after k1)
    float* cfull = (float*)shi;   // 16 MB, aliases k1-only bf16 buffers

    kprep<<<dim3(BN * TT * DD / (256 * 8), 3), 256, 0, stream>>>(
        src, mem, shi, slo, mhirm, mlorm, mhi, rowmaxU);
    k1_mfma<<<dim3(SS / 128, TT / 128, BN), 256, 0, stream>>>(
        shi, slo, mhirm, mlorm, lens, alignb, rowmaxU);
    k3_segsum<<<dim3(SS / 1024, NSEG, BN), 256, 0, stream>>>(alignb, rowmaxU, lens, segsum);
    k4_prefix<<<dim3(SS / 256, BN), 256, 0, stream>>>(segsum);
    k5_scan<<<dim3(NSEG, BN), 256, 0, stream>>>(alignb, rowmaxU, segsum, lens);
    k6_context<<<dim3(BN, TT / 16), 256, 0, stream>>>(alignb, mhi, lens, cfull);
    k7_out<<<dim3(TT / 32, BN), 256, 0, stream>>>(cfull, src, Wout, attn);
}

// Round 10
// 380.778 us; speedup vs baseline: 1.1492x; 1.1110x over previous
//
#include <hip/hip_runtime.h>
#include <math.h>

// Problem constants (B,T,S,D fixed by the reference).
#define BN 8
#define TT 2048
#define SS 2048
#define DD 256
#define NSEG 128
#define SEGLEN 16   // TT / NSEG

typedef __attribute__((ext_vector_type(8))) short short8;
typedef __attribute__((ext_vector_type(4))) float floatx4;

__device__ __forceinline__ unsigned short f2bf_rne(float f) {
    unsigned int u = __float_as_uint(f);
    u = (u + 0x7FFFu + ((u >> 16) & 1u)) >> 16;
    return (unsigned short)u;
}
__device__ __forceinline__ float bf2f(unsigned short h) {
    return __uint_as_float(((unsigned int)h) << 16);
}
// Order-preserving float<->uint for atomicMax-based rowmax.
__device__ __forceinline__ unsigned int fenc(float f) {
    unsigned int b = __float_as_uint(f);
    return (b & 0x80000000u) ? ~b : (b | 0x80000000u);
}
__device__ __forceinline__ float fdec(unsigned int u) {
    return __uint_as_float((u & 0x80000000u) ? (u & 0x7FFFFFFFu) : ~u);
}

// Async global->LDS DMA, 16 B per lane.  LDS dest must be wave-uniform base
// + lane*16 (m104/m108) — all call sites below satisfy this.
__device__ __forceinline__ void async16(const unsigned short* g, unsigned short* l) {
    __builtin_amdgcn_global_load_lds(
        (const __attribute__((address_space(1))) unsigned int*)g,
        (__attribute__((address_space(3))) unsigned int*)l,
        16, 0, 0);
}

// ---------------------------------------------------------------------------
// KPREP: fused preprocessing (one launch).
//   y=0: source fp32 -> bf16 hi/lo split, row-major; zero-init rowmaxU.
//   y=1: memory_bank fp32 -> bf16 hi/lo split, row-major.
//   y=2: memory_bank -> MFMA B-fragment layout, single bf16 (old k6pre).
// All three sub-grids are 2048 blocks of 256 threads.
// ---------------------------------------------------------------------------
__global__ __launch_bounds__(256) void kprep(
    const float* __restrict__ src, const float* __restrict__ mem,
    unsigned short* __restrict__ shi, unsigned short* __restrict__ slo,
    unsigned short* __restrict__ mhirm, unsigned short* __restrict__ mlorm,
    unsigned short* __restrict__ mhi, unsigned int* __restrict__ rowmaxU)
{
    if (blockIdx.y == 2) {                    // ---- B-fragment relayout ----
        const int gid = blockIdx.x * 256 + threadIdx.x;
        const int lane = gid & 63;
        const int dt   = (gid >> 6) & 15;
        const int c    = (gid >> 10) & 63;
        const int b    = gid >> 16;
        const int quad = lane >> 4, n = lane & 15;
        const int s = c * 32 + quad * 8;
        const int d = dt * 16 + n;
        const float* srcp = mem + ((size_t)b * SS + s) * DD + d;
        short8 hi;
#pragma unroll
        for (int j = 0; j < 8; j++)
            hi[j] = (short)f2bf_rne(srcp[(size_t)j * DD]);
        *(short8*)(mhi + (size_t)gid * 8) = hi;
        return;
    }
    if (blockIdx.y == 0 && blockIdx.x < (BN * TT / 256))
        rowmaxU[blockIdx.x * 256 + threadIdx.x] = 0u;
    const float* in; unsigned short *oh, *ol;
    if (blockIdx.y == 0) { in = src; oh = shi; ol = slo; }
    else                 { in = mem; oh = mhirm; ol = mlorm; }
    const size_t base = ((size_t)blockIdx.x * 256 + threadIdx.x) * 8;
    float4 v0 = *(const float4*)(in + base);
    float4 v1 = *(const float4*)(in + base + 4);
    float f[8] = {v0.x, v0.y, v0.z, v0.w, v1.x, v1.y, v1.z, v1.w};
    short8 hv, lv;
#pragma unroll
    for (int j = 0; j < 8; j++) {
        unsigned short h = f2bf_rne(f[j]);
        hv[j] = (short)h;
        lv[j] = (short)f2bf_rne(f[j] - bf2f(h));
    }
    *(short8*)(oh + base) = hv;
    *(short8*)(ol + base) = lv;
}

// ---------------------------------------------------------------------------
// K1: align = src @ mem^T via split-bf16 MFMA (3-term), fp32 acc.
// Epilogue computes the masked per-row tile max from the acc registers
// (shfl reduce over the 16 m-lanes) and atomicMax's it into rowmaxU.
// ---------------------------------------------------------------------------
__global__ __launch_bounds__(256) void k1_mfma(
    const unsigned short* __restrict__ shi, const unsigned short* __restrict__ slo,
    const unsigned short* __restrict__ mhirm, const unsigned short* __restrict__ mlorm,
    const int* __restrict__ lens, float* __restrict__ alignb,
    unsigned int* __restrict__ rowmaxU)
{
    const int b  = blockIdx.z;
    const int len = lens[b];
    const int s0 = blockIdx.x * 128;
    if (s0 >= len) return;
    const int t0 = blockIdx.y * 128;
    const int tid = threadIdx.x;
    const int wave = tid >> 6, lane = tid & 63;
    const int wt = wave & 1, wsb = wave >> 1;
    const int quad = lane >> 4, m = lane & 15;

    __shared__ unsigned short ldsAh[128 * 32];
    __shared__ unsigned short ldsAl[128 * 32];
    __shared__ unsigned short ldsBh[128 * 32];
    __shared__ unsigned short ldsBl[128 * 32];

    const int srow = tid >> 2, sk4 = (tid & 3) * 8;
    const size_t aBase = ((size_t)(b * TT + t0 + srow)) * DD + sk4;
    const size_t bBase = ((size_t)(b * SS + s0 + srow)) * DD + sk4;
    const size_t aBase2 = aBase + (size_t)64 * DD;
    const size_t bBase2 = bBase + (size_t)64 * DD;
    const int lo1 = tid * 8, lo2 = tid * 8 + 2048;

    floatx4 acc[4][4];
#pragma unroll
    for (int i = 0; i < 4; i++)
#pragma unroll
        for (int j = 0; j < 4; j++) acc[i][j] = (floatx4)0.f;

    for (int kc = 0; kc < 8; kc++) {
        const int ko = kc * 32;
        __syncthreads();
        async16(shi   + aBase  + ko, ldsAh + lo1);
        async16(shi   + aBase2 + ko, ldsAh + lo2);
        async16(slo   + aBase  + ko, ldsAl + lo1);
        async16(slo   + aBase2 + ko, ldsAl + lo2);
        async16(mhirm + bBase  + ko, ldsBh + lo1);
        async16(mhirm + bBase2 + ko, ldsBh + lo2);
        async16(mlorm + bBase  + ko, ldsBl + lo1);
        async16(mlorm + bBase2 + ko, ldsBl + lo2);
        __syncthreads();

        short8 Ah[4], Al[4], Bh[4], Bl[4];
#pragma unroll
        for (int f = 0; f < 4; f++) {
            const int ra = (wt * 64 + f * 16 + m) * 32 + quad * 8;
            const int rb = (wsb * 64 + f * 16 + m) * 32 + quad * 8;
            Ah[f] = *(const short8*)&ldsAh[ra];
            Al[f] = *(const short8*)&ldsAl[ra];
            Bh[f] = *(const short8*)&ldsBh[rb];
            Bl[f] = *(const short8*)&ldsBl[rb];
        }
#pragma unroll
        for (int mf = 0; mf < 4; mf++)
#pragma unroll
            for (int nf = 0; nf < 4; nf++) {
                acc[mf][nf] = __builtin_amdgcn_mfma_f32_16x16x32_bf16(
                    Ah[mf], Bh[nf], acc[mf][nf], 0, 0, 0);
                acc[mf][nf] = __builtin_amdgcn_mfma_f32_16x16x32_bf16(
                    Al[mf], Bh[nf], acc[mf][nf], 0, 0, 0);
                acc[mf][nf] = __builtin_amdgcn_mfma_f32_16x16x32_bf16(
                    Ah[mf], Bl[nf], acc[mf][nf], 0, 0, 0);
            }
    }

#pragma unroll
    for (int mf = 0; mf < 4; mf++)
#pragma unroll
        for (int reg = 0; reg < 4; reg++) {
            const int t = t0 + wt * 64 + mf * 16 + quad * 4 + reg;
            float* row = alignb + ((size_t)(b * TT + t)) * SS + s0 + wsb * 64 + m;
#pragma unroll
            for (int nf = 0; nf < 4; nf++)
                row[nf * 16] = acc[mf][nf][reg];
        }

    // Epilogue 2: masked per-row max of this tile-half -> atomicMax.
    if (s0 + wsb * 64 < len) {
#pragma unroll
        for (int mf = 0; mf < 4; mf++)
#pragma unroll
            for (int reg = 0; reg < 4; reg++) {
                float mx = -INFINITY;
#pragma unroll
                for (int nf = 0; nf < 4; nf++) {
                    const int col = s0 + wsb * 64 + nf * 16 + m;
                    mx = (col < len) ? fmaxf(mx, acc[mf][nf][reg]) : mx;
                }
#pragma unroll
                for (int off = 1; off < 16; off <<= 1)       // reduce over m-lanes
                    mx = fmaxf(mx, __shfl_xor(mx, off, 64));
                if (m == 0) {
                    const int t = t0 + wt * 64 + mf * 16 + quad * 4 + reg;
                    atomicMax(&rowmaxU[b * TT + t], fenc(mx));
                }
            }
    }
}

// ---------------------------------------------------------------------------
// K3: per-(b,seg,s) sum over the segment's 16 rows of e = exp(align - max).
// float4-vectorized: 4 s-columns per thread, 4-row unroll for MLP.
// ---------------------------------------------------------------------------
__global__ __launch_bounds__(256) void k3_segsum(
    const float* __restrict__ alignb, const unsigned int* __restrict__ rowmaxU,
    const int* __restrict__ lens, float* __restrict__ segsum)
{
    const int b = blockIdx.z, seg = blockIdx.y;
    const int s4 = (blockIdx.x * 256 + threadIdx.x) * 4;
    const int len = lens[b];
    float4 sum = {0.f, 0.f, 0.f, 0.f};
    if (s4 < len) {
        const float* base = alignb + ((size_t)b * TT + seg * SEGLEN) * SS + s4;
        const unsigned int* rmu = rowmaxU + b * TT + seg * SEGLEN;
        const bool v1 = (s4 + 1) < len, v2 = (s4 + 2) < len, v3 = (s4 + 3) < len;
#pragma unroll 4
        for (int r = 0; r < SEGLEN; r++) {
            const float m = fdec(rmu[r]);
            float4 v = *(const float4*)(base + (size_t)r * SS);
            sum.x += __expf(v.x - m);
            sum.y += v1 ? __expf(v.y - m) : 0.f;
            sum.z += v2 ? __expf(v.z - m) : 0.f;
            sum.w += v3 ? __expf(v.w - m) : 0.f;
        }
    }
    *(float4*)(segsum + ((size_t)b * NSEG + seg) * SS + s4) = sum;
}

// ---------------------------------------------------------------------------
// K4: exclusive prefix over the 128 segments, per (b,s) column, in place.
// ---------------------------------------------------------------------------
__global__ __launch_bounds__(256) void k4_prefix(float* __restrict__ segsum)
{
    const int b = blockIdx.y;
    const int s = blockIdx.x * 256 + threadIdx.x;
    float run = 0.f;
    for (int g = 0; g < NSEG / 8; g++) {
        float v[8];
#pragma unroll
        for (int i = 0; i < 8; i++)
            v[i] = segsum[((size_t)b * NSEG + g * 8 + i) * SS + s];
#pragma unroll
        for (int i = 0; i < 8; i++) {
            segsum[((size_t)b * NSEG + g * 8 + i) * SS + s] = run;
            run += v[i];
        }
    }
}

// ---------------------------------------------------------------------------
// K5: full-row scan + normalize, 16 t-rows per block (NSEG=128 -> 1024
// blocks, ~4 blocks/CU).  No big LDS tile; writes the FINAL normalized
// align_vectors in place.  Cols >= len get 0.
// ---------------------------------------------------------------------------
__global__ __launch_bounds__(256) void k5_scan(
    float* __restrict__ alignb, const unsigned int* __restrict__ rowmaxU,
    const float* __restrict__ segsum, const int* __restrict__ lens)
{
    const int seg = blockIdx.x, b = blockIdx.y;
    const int len = lens[b];
    const int c0 = threadIdx.x * 8;
    const int lane = threadIdx.x & 63, wid = threadIdx.x >> 6;
    const bool anyv = c0 < len;

    __shared__ float red[8];

    float psum[8];
    {
        const float* sp = segsum + ((size_t)b * NSEG + seg) * SS + c0;
        float4 a = *(const float4*)sp, c = *(const float4*)(sp + 4);
        psum[0] = a.x; psum[1] = a.y; psum[2] = a.z; psum[3] = a.w;
        psum[4] = c.x; psum[5] = c.y; psum[6] = c.z; psum[7] = c.w;
    }

    float* rowp = alignb + ((size_t)(b * TT + seg * SEGLEN)) * SS + c0;

    float avn[8] = {0.f, 0.f, 0.f, 0.f, 0.f, 0.f, 0.f, 0.f};
    if (anyv) {
        float4 a = *(const float4*)rowp, c = *(const float4*)(rowp + 4);
        avn[0] = a.x; avn[1] = a.y; avn[2] = a.z; avn[3] = a.w;
        avn[4] = c.x; avn[5] = c.y; avn[6] = c.z; avn[7] = c.w;
    }

    for (int r = 0; r < SEGLEN; r++) {
        const int t = seg * SEGLEN + r;
        const float m = fdec(rowmaxU[b * TT + t]);
        float av[8];
#pragma unroll
        for (int j = 0; j < 8; j++) av[j] = avn[j];
        if (anyv && r + 1 < SEGLEN) {          // prefetch next row
            const float* np = rowp + (size_t)(r + 1) * SS;
            float4 a = *(const float4*)np, c = *(const float4*)(np + 4);
            avn[0] = a.x; avn[1] = a.y; avn[2] = a.z; avn[3] = a.w;
            avn[4] = c.x; avn[5] = c.y; avn[6] = c.z; avn[7] = c.w;
        }
        float u[8], rsum = 0.f;
#pragma unroll
        for (int j = 0; j < 8; j++) {
            float e = (c0 + j < len) ? __expf(av[j] - m) : 0.f;
            float div = (t == 0) ? 1.0f : (psum[j] + 1e-20f);
            u[j] = e * __builtin_amdgcn_rcpf(div);
            psum[j] += e;
            rsum += u[j];
        }
#pragma unroll
        for (int off = 32; off > 0; off >>= 1)
            rsum += __shfl_down(rsum, off, 64);
        const int pp = (r & 1) * 4;
        if (lane == 0) red[pp + wid] = rsum;
        __syncthreads();
        const float inv = 1.0f / (red[pp] + red[pp + 1] + red[pp + 2] + red[pp + 3]);
        float* wp = rowp + (size_t)r * SS;
        float4 o0 = {u[0] * inv, u[1] * inv, u[2] * inv, u[3] * inv};
        float4 o1 = {u[4] * inv, u[5] * inv, u[6] * inv, u[7] * inv};
        *(float4*)wp = o0;
        *(float4*)(wp + 4) = o1;
    }
}

// ---------------------------------------------------------------------------
// K6: c = align_vectors @ mem, single-bf16 MFMA.  32-row t-tiles (grid
// (TT/32, BN) = 512 blocks; consecutive blocks share b so each XCD's L2
// holds one 1 MB mhi panel).  A staged via the verified 2-barrier
// global_load_lds chunk loop (32 rows x 512 B = 16 KB, pre-swizzled global
// source, linear LDS dest, ds_read at the same XOR -> bank-balanced).
// vs round 6: tile 16->32 rows halves total mhi B-panel traffic (0.5 GB)
// and doubles MFMA per B-load; staged-A fix (round 6) retained.
// ---------------------------------------------------------------------------
__global__ __launch_bounds__(256, 4) void k6_context(
    const float* __restrict__ alignb, const unsigned short* __restrict__ mhi,
    const int* __restrict__ lens, float* __restrict__ cfull)
{
    const int t0 = blockIdx.x * 32;
    const int b  = blockIdx.y;
    const int tid  = threadIdx.x;
    const int wave = tid >> 6, lane = tid & 63;
    const int quad = lane >> 4, m = lane & 15;

    const int len = lens[b];
    int nch = (len + 127) >> 7;            // 128-col chunks of s
    if (nch > 16) nch = 16;

    __shared__ __align__(16) unsigned char ldsA[32 * 512];   // [32 rows][512 B]

    floatx4 acc[2][4];
#pragma unroll
    for (int i = 0; i < 2; i++)
#pragma unroll
        for (int j = 0; j < 4; j++) acc[i][j] = (floatx4)0.f;

    const char* aRow0 = (const char*)(alignb + ((size_t)(b * TT + t0)) * SS);

    // Stage addresses: 4 issues x 4 KB; flat = i*4096 + tid*16, row = flat>>9.
    const char* srcs[4];
    int flats[4];
#pragma unroll
    for (int i = 0; i < 4; i++) {
        const int flat = i * 4096 + tid * 16;
        const int row  = flat >> 9;
        const int col  = (flat ^ ((row & 7) << 4)) & 511;  // pre-swizzled src
        flats[i] = flat;
        srcs[i]  = aRow0 + (size_t)row * (SS * 4) + col;
    }

    for (int cc = 0; cc < nch; cc++) {
        __syncthreads();                     // previous chunk's reads done
#pragma unroll
        for (int i = 0; i < 4; i++)
            async16((const unsigned short*)(srcs[i] + cc * 512),
                    (unsigned short*)(ldsA + flats[i]));
        __syncthreads();                     // drains vmcnt(0) then barrier

#pragma unroll
        for (int c4 = 0; c4 < 4; c4++) {
            const int c = cc * 4 + c4;
            short8 Bf[4];
#pragma unroll
            for (int j = 0; j < 4; j++) {
                const int dt = wave * 4 + j;
                Bf[j] = *(const short8*)(mhi +
                    (((size_t)(b * 64 + c) * 16 + dt) * 64 + lane) * 8);
            }
#pragma unroll
            for (int mf = 0; mf < 2; mf++) {
                // row = mf*16 + m; (row&7) == (m&7) since 16 ≡ 0 (mod 8)
                const int lb = ((mf * 16 + m) * 512 + c4 * 128 + quad * 32)
                               ^ ((m & 7) << 4);
                float4 v0 = *(const float4*)(ldsA + lb);
                float4 v1 = *(const float4*)(ldsA + (lb ^ 16));
                union { short8 s; unsigned int u[4]; } pk;   // bf16 RTZ pack
                pk.u[0] = (__float_as_uint(v0.x) >> 16) | (__float_as_uint(v0.y) & 0xFFFF0000u);
                pk.u[1] = (__float_as_uint(v0.z) >> 16) | (__float_as_uint(v0.w) & 0xFFFF0000u);
                pk.u[2] = (__float_as_uint(v1.x) >> 16) | (__float_as_uint(v1.y) & 0xFFFF0000u);
                pk.u[3] = (__float_as_uint(v1.z) >> 16) | (__float_as_uint(v1.w) & 0xFFFF0000u);
#pragma unroll
                for (int j = 0; j < 4; j++)
                    acc[mf][j] = __builtin_amdgcn_mfma_f32_16x16x32_bf16(
                        pk.s, Bf[j], acc[mf][j], 0, 0, 0);
            }
        }
    }

#pragma unroll
    for (int mf = 0; mf < 2; mf++)
#pragma unroll
        for (int j = 0; j < 4; j++) {
            const int d = wave * 64 + j * 16 + m;
#pragma unroll
            for (int reg = 0; reg < 4; reg++) {
                const int t = t0 + mf * 16 + quad * 4 + reg;
                cfull[((size_t)(b * TT + t)) * DD + d] = acc[mf][j][reg];
            }
        }
}

// ---------------------------------------------------------------------------
// K7: attn_h = tanh([c, source] @ W_out); c is complete (no partials).
// ---------------------------------------------------------------------------
__global__ __launch_bounds__(256) void k7_out(
    const float* __restrict__ cfull, const float* __restrict__ src,
    const float* __restrict__ W, float* __restrict__ attn)
{
    const int b = blockIdx.y;
    const int t0 = blockIdx.x * 32;
    const int tid = threadIdx.x;
    const int tx = tid & 63, ty = tid >> 6;

    __shared__ __align__(16) float wT[32][256];
    __shared__ float xT[32][32];

    float4 acc[8];
#pragma unroll
    for (int i = 0; i < 8; i++) acc[i] = make_float4(0.f, 0.f, 0.f, 0.f);

    for (int k0 = 0; k0 < 2 * DD; k0 += 32) {
        __syncthreads();
#pragma unroll
        for (int it = 0; it < 8; it++) {
            int f = tid + it * 256;
            int kr = f >> 6, col = (f & 63) * 4;
            *(float4*)&wT[kr][col] =
                *(const float4*)(W + (size_t)(k0 + kr) * DD + col);
        }
#pragma unroll
        for (int rep = 0; rep < 4; rep++) {
            int idx = tid + rep * 256;
            int r = idx >> 5, c = idx & 31;
            int k = k0 + c;
            float x;
            if (k < DD) {
                x = cfull[((size_t)b * TT + t0 + r) * DD + k];
            } else {
                x = src[((size_t)b * TT + t0 + r) * DD + (k - DD)];
            }
            xT[r][c] = x;
        }
        __syncthreads();
#pragma unroll
        for (int kk = 0; kk < 32; kk++) {
            float4 w4 = *(const float4*)&wT[kk][tx * 4];
#pragma unroll
            for (int r4 = 0; r4 < 8; r4++) {
                float x = xT[ty + r4 * 4][kk];
                acc[r4].x += x * w4.x; acc[r4].y += x * w4.y;
                acc[r4].z += x * w4.z; acc[r4].w += x * w4.w;
            }
        }
    }
#pragma unroll
    for (int r4 = 0; r4 < 8; r4++) {
        const int t = t0 + ty + r4 * 4;
        float4 o;
        o.x = tanhf(acc[r4].x); o.y = tanhf(acc[r4].y);
        o.z = tanhf(acc[r4].z); o.w = tanhf(acc[r4].w);
        *(float4*)(attn + ((size_t)b * TT + t) * DD + tx * 4) = o;
    }
}

// ---------------------------------------------------------------------------
extern "C" void kernel_launch(void* const* d_in, const int* in_sizes, int n_in,
                              void* d_out, int out_size, void* d_ws, size_t ws_size,
                              hipStream_t stream)
{
    const float* src  = (const float*)d_in[0];   // [B,T,D]
    const float* mem  = (const float*)d_in[1];   // [B,S,D]
    const float* Wout = (const float*)d_in[2];   // [2D,D]
    const int*   lens = (const int*)d_in[3];     // [B]

    float* out    = (float*)d_out;
    float* attn   = out;                               // [B,T,D]
    float* alignb = out + (size_t)BN * TT * DD;        // [B,T,S] scratch -> final

    unsigned int* rowmaxU = (unsigned int*)d_ws;                       // 64 KB
    float* segsum = (float*)(rowmaxU + (size_t)BN * TT);               // 8 MB
    unsigned short* mhi = (unsigned short*)(segsum + (size_t)BN * NSEG * SS); // 8 MB
    unsigned short* shi   = mhi + (size_t)BN * SS * DD;                // 8 MB (dead after k1)
    unsigned short* slo   = shi + (size_t)BN * TT * DD;                // 8 MB (dead after k1)
    unsigned short* mhirm = slo + (size_t)BN * TT * DD;                // 8 MB (dead after k1)
    unsigned short* mlorm = mhirm + (size_t)BN * SS * DD;              // 8 MB (dead after k1)
    float* cfull = (float*)shi;   // 16 MB, aliases k1-only bf16 buffers

    kprep<<<dim3(BN * TT * DD / (256 * 8), 3), 256, 0, stream>>>(
        src, mem, shi, slo, mhirm, mlorm, mhi, rowmaxU);
    k1_mfma<<<dim3(SS / 128, TT / 128, BN), 256, 0, stream>>>(
        shi, slo, mhirm, mlorm, lens, alignb, rowmaxU);
    k3_segsum<<<dim3(SS / 1024, NSEG, BN), 256, 0, stream>>>(alignb, rowmaxU, lens, segsum);
    k4_prefix<<<dim3(SS / 256, BN), 256, 0, stream>>>(segsum);
    k5_scan<<<dim3(NSEG, BN), 256, 0, stream>>>(alignb, rowmaxU, segsum, lens);
    k6_context<<<dim3(TT / 32, BN), 256, 0, stream>>>(alignb, mhi, lens, cfull);
    k7_out<<<dim3(TT / 32, BN), 256, 0, stream>>>(cfull, src, Wout, attn);
}

// Round 15
// 373.209 us; speedup vs baseline: 1.1726x; 1.0203x over previous
//
#include <hip/hip_runtime.h>
#include <hip/hip_fp16.h>
#include <math.h>

// Problem constants (B,T,S,D fixed by the reference).
#define BN 8
#define TT 2048
#define SS 2048
#define DD 256
#define NSEG 128
#define SEGLEN 16   // TT / NSEG

typedef __attribute__((ext_vector_type(8))) short short8;
typedef __attribute__((ext_vector_type(4))) float floatx4;
typedef _Float16 half8 __attribute__((ext_vector_type(8)));
typedef __fp16 fp16x2 __attribute__((ext_vector_type(2)));   // cvt_pkrtz return type

__device__ __forceinline__ unsigned short f2h_rn(float f) {
    return __half_as_ushort(__float2half_rn(f));
}
__device__ __forceinline__ float h2f(unsigned short u) {
    return __half2float(__ushort_as_half(u));
}
// Order-preserving float<->uint for atomicMax-based rowmax.
__device__ __forceinline__ unsigned int fenc(float f) {
    unsigned int b = __float_as_uint(f);
    return (b & 0x80000000u) ? ~b : (b | 0x80000000u);
}
__device__ __forceinline__ float fdec(unsigned int u) {
    return __uint_as_float((u & 0x80000000u) ? (u & 0x7FFFFFFFu) : ~u);
}

// Async global->LDS DMA, 16 B per lane.  LDS dest must be wave-uniform base
// + lane*16 (m104/m108) — all call sites below satisfy this.
__device__ __forceinline__ void async16(const unsigned short* g, unsigned short* l) {
    __builtin_amdgcn_global_load_lds(
        (const __attribute__((address_space(1))) unsigned int*)g,
        (__attribute__((address_space(3))) unsigned int*)l,
        16, 0, 0);
}

// ---------------------------------------------------------------------------
// KPREP: fused preprocessing (one launch).
//   y=0: source fp32 -> fp16 hi + fp16 residual (asymmetric split for k1's
//        2-term MFMA; A-side error ~2^-22); zero-init rowmaxU.
//   y=1: memory_bank fp32 -> single fp16 row-major (B-side error 2^-11 —
//        the dominant k1 term, ~0.003 on logits; analyzed safe).
//   y=2: memory_bank -> MFMA B-fragment layout, fp16.
// ---------------------------------------------------------------------------
__global__ __launch_bounds__(256) void kprep(
    const float* __restrict__ src, const float* __restrict__ mem,
    unsigned short* __restrict__ shi, unsigned short* __restrict__ slo,
    unsigned short* __restrict__ mhirm,
    unsigned short* __restrict__ mhi, unsigned int* __restrict__ rowmaxU)
{
    if (blockIdx.y == 2) {                    // ---- B-fragment relayout ----
        const int gid = blockIdx.x * 256 + threadIdx.x;
        const int lane = gid & 63;
        const int dt   = (gid >> 6) & 15;
        const int c    = (gid >> 10) & 63;
        const int b    = gid >> 16;
        const int quad = lane >> 4, n = lane & 15;
        const int s = c * 32 + quad * 8;
        const int d = dt * 16 + n;
        const float* srcp = mem + ((size_t)b * SS + s) * DD + d;
        short8 hi;
#pragma unroll
        for (int j = 0; j < 8; j++)
            hi[j] = (short)f2h_rn(srcp[(size_t)j * DD]);
        *(short8*)(mhi + (size_t)gid * 8) = hi;
        return;
    }
    if (blockIdx.y == 0 && blockIdx.x < (BN * TT / 256))
        rowmaxU[blockIdx.x * 256 + threadIdx.x] = 0u;
    const size_t base = ((size_t)blockIdx.x * 256 + threadIdx.x) * 8;
    if (blockIdx.y == 0) {                    // ---- source: hi/lo split ----
        float4 v0 = *(const float4*)(src + base);
        float4 v1 = *(const float4*)(src + base + 4);
        float f[8] = {v0.x, v0.y, v0.z, v0.w, v1.x, v1.y, v1.z, v1.w};
        short8 hv, lv;
#pragma unroll
        for (int j = 0; j < 8; j++) {
            unsigned short h = f2h_rn(f[j]);
            hv[j] = (short)h;
            lv[j] = (short)f2h_rn(f[j] - h2f(h));
        }
        *(short8*)(shi + base) = hv;
        *(short8*)(slo + base) = lv;
    } else {                                  // ---- memory: single fp16 ----
        float4 v0 = *(const float4*)(mem + base);
        float4 v1 = *(const float4*)(mem + base + 4);
        float f[8] = {v0.x, v0.y, v0.z, v0.w, v1.x, v1.y, v1.z, v1.w};
        short8 hv;
#pragma unroll
        for (int j = 0; j < 8; j++) hv[j] = (short)f2h_rn(f[j]);
        *(short8*)(mhirm + base) = hv;
    }
}

// ---------------------------------------------------------------------------
// K1: align = src @ mem^T via 2-term fp16 MFMA (A = Ah + Al split, B single),
// fp32 acc.  vs bf16 3-term: 2/3 the MFMA, 3/4 the staging (3 LDS bufs,
// 6 async16/kc), 24 KB LDS.  Logit error ~0.003 (B-quantization bound).
// Epilogue: masked per-row tile max from acc -> atomicMax (ordered-uint).
// ---------------------------------------------------------------------------
__global__ __launch_bounds__(256) void k1_mfma(
    const unsigned short* __restrict__ shi, const unsigned short* __restrict__ slo,
    const unsigned short* __restrict__ mhirm,
    const int* __restrict__ lens, float* __restrict__ alignb,
    unsigned int* __restrict__ rowmaxU)
{
    const int b  = blockIdx.z;
    const int len = lens[b];
    const int s0 = blockIdx.x * 128;
    if (s0 >= len) return;
    const int t0 = blockIdx.y * 128;
    const int tid = threadIdx.x;
    const int wave = tid >> 6, lane = tid & 63;
    const int wt = wave & 1, wsb = wave >> 1;
    const int quad = lane >> 4, m = lane & 15;

    __shared__ unsigned short ldsAh[128 * 32];
    __shared__ unsigned short ldsAl[128 * 32];
    __shared__ unsigned short ldsB[128 * 32];

    const int srow = tid >> 2, sk4 = (tid & 3) * 8;
    const size_t aBase = ((size_t)(b * TT + t0 + srow)) * DD + sk4;
    const size_t bBase = ((size_t)(b * SS + s0 + srow)) * DD + sk4;
    const size_t aBase2 = aBase + (size_t)64 * DD;
    const size_t bBase2 = bBase + (size_t)64 * DD;
    const int lo1 = tid * 8, lo2 = tid * 8 + 2048;

    floatx4 acc[4][4];
#pragma unroll
    for (int i = 0; i < 4; i++)
#pragma unroll
        for (int j = 0; j < 4; j++) acc[i][j] = (floatx4)0.f;

    for (int kc = 0; kc < 8; kc++) {
        const int ko = kc * 32;
        __syncthreads();
        async16(shi   + aBase  + ko, ldsAh + lo1);
        async16(shi   + aBase2 + ko, ldsAh + lo2);
        async16(slo   + aBase  + ko, ldsAl + lo1);
        async16(slo   + aBase2 + ko, ldsAl + lo2);
        async16(mhirm + bBase  + ko, ldsB + lo1);
        async16(mhirm + bBase2 + ko, ldsB + lo2);
        __syncthreads();

        half8 Ah[4], Al[4], Bf[4];
#pragma unroll
        for (int f = 0; f < 4; f++) {
            const int ra = (wt * 64 + f * 16 + m) * 32 + quad * 8;
            const int rb = (wsb * 64 + f * 16 + m) * 32 + quad * 8;
            Ah[f] = *(const half8*)&ldsAh[ra];
            Al[f] = *(const half8*)&ldsAl[ra];
            Bf[f] = *(const half8*)&ldsB[rb];
        }
#pragma unroll
        for (int mf = 0; mf < 4; mf++)
#pragma unroll
            for (int nf = 0; nf < 4; nf++) {
                acc[mf][nf] = __builtin_amdgcn_mfma_f32_16x16x32_f16(
                    Ah[mf], Bf[nf], acc[mf][nf], 0, 0, 0);
                acc[mf][nf] = __builtin_amdgcn_mfma_f32_16x16x32_f16(
                    Al[mf], Bf[nf], acc[mf][nf], 0, 0, 0);
            }
    }

#pragma unroll
    for (int mf = 0; mf < 4; mf++)
#pragma unroll
        for (int reg = 0; reg < 4; reg++) {
            const int t = t0 + wt * 64 + mf * 16 + quad * 4 + reg;
            float* row = alignb + ((size_t)(b * TT + t)) * SS + s0 + wsb * 64 + m;
#pragma unroll
            for (int nf = 0; nf < 4; nf++)
                row[nf * 16] = acc[mf][nf][reg];
        }

    // Epilogue 2: masked per-row max of this tile-half -> atomicMax.
    if (s0 + wsb * 64 < len) {
#pragma unroll
        for (int mf = 0; mf < 4; mf++)
#pragma unroll
            for (int reg = 0; reg < 4; reg++) {
                float mx = -INFINITY;
#pragma unroll
                for (int nf = 0; nf < 4; nf++) {
                    const int col = s0 + wsb * 64 + nf * 16 + m;
                    mx = (col < len) ? fmaxf(mx, acc[mf][nf][reg]) : mx;
                }
#pragma unroll
                for (int off = 1; off < 16; off <<= 1)       // reduce over m-lanes
                    mx = fmaxf(mx, __shfl_xor(mx, off, 64));
                if (m == 0) {
                    const int t = t0 + wt * 64 + mf * 16 + quad * 4 + reg;
                    atomicMax(&rowmaxU[b * TT + t], fenc(mx));
                }
            }
    }
}

// ---------------------------------------------------------------------------
// K3: per-(b,seg,s) sum over the segment's 16 rows of e = exp(align - max).
// float4-vectorized: 4 s-columns per thread, 4-row unroll for MLP.
// ---------------------------------------------------------------------------
__global__ __launch_bounds__(256) void k3_segsum(
    const float* __restrict__ alignb, const unsigned int* __restrict__ rowmaxU,
    const int* __restrict__ lens, float* __restrict__ segsum)
{
    const int b = blockIdx.z, seg = blockIdx.y;
    const int s4 = (blockIdx.x * 256 + threadIdx.x) * 4;
    const int len = lens[b];
    float4 sum = {0.f, 0.f, 0.f, 0.f};
    if (s4 < len) {
        const float* base = alignb + ((size_t)b * TT + seg * SEGLEN) * SS + s4;
        const unsigned int* rmu = rowmaxU + b * TT + seg * SEGLEN;
        const bool v1 = (s4 + 1) < len, v2 = (s4 + 2) < len, v3 = (s4 + 3) < len;
#pragma unroll 4
        for (int r = 0; r < SEGLEN; r++) {
            const float m = fdec(rmu[r]);
            float4 v = *(const float4*)(base + (size_t)r * SS);
            sum.x += __expf(v.x - m);
            sum.y += v1 ? __expf(v.y - m) : 0.f;
            sum.z += v2 ? __expf(v.z - m) : 0.f;
            sum.w += v3 ? __expf(v.w - m) : 0.f;
        }
    }
    *(float4*)(segsum + ((size_t)b * NSEG + seg) * SS + s4) = sum;
}

// ---------------------------------------------------------------------------
// K4: exclusive prefix over the 128 segments, per (b,s) column, in place.
// ---------------------------------------------------------------------------
__global__ __launch_bounds__(256) void k4_prefix(float* __restrict__ segsum)
{
    const int b = blockIdx.y;
    const int s = blockIdx.x * 256 + threadIdx.x;
    float run = 0.f;
    for (int g = 0; g < NSEG / 8; g++) {
        float v[8];
#pragma unroll
        for (int i = 0; i < 8; i++)
            v[i] = segsum[((size_t)b * NSEG + g * 8 + i) * SS + s];
#pragma unroll
        for (int i = 0; i < 8; i++) {
            segsum[((size_t)b * NSEG + g * 8 + i) * SS + s] = run;
            run += v[i];
        }
    }
}

// ---------------------------------------------------------------------------
// K5: full-row scan + normalize, 16 t-rows per block (NSEG=128 -> 1024
// blocks, ~4 blocks/CU).  No big LDS tile; writes the FINAL normalized
// align_vectors in place.  Cols >= len get 0.
// ---------------------------------------------------------------------------
__global__ __launch_bounds__(256) void k5_scan(
    float* __restrict__ alignb, const unsigned int* __restrict__ rowmaxU,
    const float* __restrict__ segsum, const int* __restrict__ lens)
{
    const int seg = blockIdx.x, b = blockIdx.y;
    const int len = lens[b];
    const int c0 = threadIdx.x * 8;
    const int lane = threadIdx.x & 63, wid = threadIdx.x >> 6;
    const bool anyv = c0 < len;

    __shared__ float red[8];

    float psum[8];
    {
        const float* sp = segsum + ((size_t)b * NSEG + seg) * SS + c0;
        float4 a = *(const float4*)sp, c = *(const float4*)(sp + 4);
        psum[0] = a.x; psum[1] = a.y; psum[2] = a.z; psum[3] = a.w;
        psum[4] = c.x; psum[5] = c.y; psum[6] = c.z; psum[7] = c.w;
    }

    float* rowp = alignb + ((size_t)(b * TT + seg * SEGLEN)) * SS + c0;

    float avn[8] = {0.f, 0.f, 0.f, 0.f, 0.f, 0.f, 0.f, 0.f};
    if (anyv) {
        float4 a = *(const float4*)rowp, c = *(const float4*)(rowp + 4);
        avn[0] = a.x; avn[1] = a.y; avn[2] = a.z; avn[3] = a.w;
        avn[4] = c.x; avn[5] = c.y; avn[6] = c.z; avn[7] = c.w;
    }

    for (int r = 0; r < SEGLEN; r++) {
        const int t = seg * SEGLEN + r;
        const float m = fdec(rowmaxU[b * TT + t]);
        float av[8];
#pragma unroll
        for (int j = 0; j < 8; j++) av[j] = avn[j];
        if (anyv && r + 1 < SEGLEN) {          // prefetch next row
            const float* np = rowp + (size_t)(r + 1) * SS;
            float4 a = *(const float4*)np, c = *(const float4*)(np + 4);
            avn[0] = a.x; avn[1] = a.y; avn[2] = a.z; avn[3] = a.w;
            avn[4] = c.x; avn[5] = c.y; avn[6] = c.z; avn[7] = c.w;
        }
        float u[8], rsum = 0.f;
#pragma unroll
        for (int j = 0; j < 8; j++) {
            float e = (c0 + j < len) ? __expf(av[j] - m) : 0.f;
            float div = (t == 0) ? 1.0f : (psum[j] + 1e-20f);
            u[j] = e * __builtin_amdgcn_rcpf(div);
            psum[j] += e;
            rsum += u[j];
        }
#pragma unroll
        for (int off = 32; off > 0; off >>= 1)
            rsum += __shfl_down(rsum, off, 64);
        const int pp = (r & 1) * 4;
        if (lane == 0) red[pp + wid] = rsum;
        __syncthreads();
        const float inv = 1.0f / (red[pp] + red[pp + 1] + red[pp + 2] + red[pp + 3]);
        float* wp = rowp + (size_t)r * SS;
        float4 o0 = {u[0] * inv, u[1] * inv, u[2] * inv, u[3] * inv};
        float4 o1 = {u[4] * inv, u[5] * inv, u[6] * inv, u[7] * inv};
        *(float4*)wp = o0;
        *(float4*)(wp + 4) = o1;
    }
}

// ---------------------------------------------------------------------------
// K6: c = align_vectors @ mem, fp16 MFMA.  32-row t-tiles (grid (TT/32, BN):
// consecutive blocks share b so each XCD's L2 holds one mhi panel).  A staged
// via the verified 2-barrier global_load_lds chunk loop (pre-swizzled global
// source, linear LDS dest, ds_read at the same XOR).  A-pack via v_cvt_pkrtz.
// ---------------------------------------------------------------------------
__global__ __launch_bounds__(256, 4) void k6_context(
    const float* __restrict__ alignb, const unsigned short* __restrict__ mhi,
    const int* __restrict__ lens, float* __restrict__ cfull)
{
    const int t0 = blockIdx.x * 32;
    const int b  = blockIdx.y;
    const int tid  = threadIdx.x;
    const int wave = tid >> 6, lane = tid & 63;
    const int quad = lane >> 4, m = lane & 15;

    const int len = lens[b];
    int nch = (len + 127) >> 7;            // 128-col chunks of s
    if (nch > 16) nch = 16;

    __shared__ __align__(16) unsigned char ldsA[32 * 512];   // [32 rows][512 B]

    floatx4 acc[2][4];
#pragma unroll
    for (int i = 0; i < 2; i++)
#pragma unroll
        for (int j = 0; j < 4; j++) acc[i][j] = (floatx4)0.f;

    const char* aRow0 = (const char*)(alignb + ((size_t)(b * TT + t0)) * SS);

    // Stage addresses: 4 issues x 4 KB; flat = i*4096 + tid*16, row = flat>>9.
    const char* srcs[4];
    int flats[4];
#pragma unroll
    for (int i = 0; i < 4; i++) {
        const int flat = i * 4096 + tid * 16;
        const int row  = flat >> 9;
        const int col  = (flat ^ ((row & 7) << 4)) & 511;  // pre-swizzled src
        flats[i] = flat;
        srcs[i]  = aRow0 + (size_t)row * (SS * 4) + col;
    }

    for (int cc = 0; cc < nch; cc++) {
        __syncthreads();                     // previous chunk's reads done
#pragma unroll
        for (int i = 0; i < 4; i++)
            async16((const unsigned short*)(srcs[i] + cc * 512),
                    (unsigned short*)(ldsA + flats[i]));
        __syncthreads();                     // drains vmcnt(0) then barrier

#pragma unroll
        for (int c4 = 0; c4 < 4; c4++) {
            const int c = cc * 4 + c4;
            half8 Bf[4];
#pragma unroll
            for (int j = 0; j < 4; j++) {
                const int dt = wave * 4 + j;
                Bf[j] = *(const half8*)(mhi +
                    (((size_t)(b * 64 + c) * 16 + dt) * 64 + lane) * 8);
            }
#pragma unroll
            for (int mf = 0; mf < 2; mf++) {
                // row = mf*16 + m; (row&7) == (m&7) since 16 ≡ 0 (mod 8)
                const int lb = ((mf * 16 + m) * 512 + c4 * 128 + quad * 32)
                               ^ ((m & 7) << 4);
                float4 v0 = *(const float4*)(ldsA + lb);
                float4 v1 = *(const float4*)(ldsA + (lb ^ 16));
                union { fp16x2 h; unsigned int u; } c0, c1, c2, c3;
                c0.h = __builtin_amdgcn_cvt_pkrtz(v0.x, v0.y);
                c1.h = __builtin_amdgcn_cvt_pkrtz(v0.z, v0.w);
                c2.h = __builtin_amdgcn_cvt_pkrtz(v1.x, v1.y);
                c3.h = __builtin_amdgcn_cvt_pkrtz(v1.z, v1.w);
                union { half8 s; unsigned int u[4]; } pk;
                pk.u[0] = c0.u; pk.u[1] = c1.u; pk.u[2] = c2.u; pk.u[3] = c3.u;
#pragma unroll
                for (int j = 0; j < 4; j++)
                    acc[mf][j] = __builtin_amdgcn_mfma_f32_16x16x32_f16(
                        pk.s, Bf[j], acc[mf][j], 0, 0, 0);
            }
        }
    }

#pragma unroll
    for (int mf = 0; mf < 2; mf++)
#pragma unroll
        for (int j = 0; j < 4; j++) {
            const int d = wave * 64 + j * 16 + m;
#pragma unroll
            for (int reg = 0; reg < 4; reg++) {
                const int t = t0 + mf * 16 + quad * 4 + reg;
                cfull[((size_t)(b * TT + t)) * DD + d] = acc[mf][j][reg];
            }
        }
}

// ---------------------------------------------------------------------------
// K7: attn_h = tanh([c, source] @ W_out); c is complete (no partials).
// ---------------------------------------------------------------------------
__global__ __launch_bounds__(256) void k7_out(
    const float* __restrict__ cfull, const float* __restrict__ src,
    const float* __restrict__ W, float* __restrict__ attn)
{
    const int b = blockIdx.y;
    const int t0 = blockIdx.x * 32;
    const int tid = threadIdx.x;
    const int tx = tid & 63, ty = tid >> 6;

    __shared__ __align__(16) float wT[32][256];
    __shared__ float xT[32][32];

    float4 acc[8];
#pragma unroll
    for (int i = 0; i < 8; i++) acc[i] = make_float4(0.f, 0.f, 0.f, 0.f);

    for (int k0 = 0; k0 < 2 * DD; k0 += 32) {
        __syncthreads();
#pragma unroll
        for (int it = 0; it < 8; it++) {
            int f = tid + it * 256;
            int kr = f >> 6, col = (f & 63) * 4;
            *(float4*)&wT[kr][col] =
                *(const float4*)(W + (size_t)(k0 + kr) * DD + col);
        }
#pragma unroll
        for (int rep = 0; rep < 4; rep++) {
            int idx = tid + rep * 256;
            int r = idx >> 5, c = idx & 31;
            int k = k0 + c;
            float x;
            if (k < DD) {
                x = cfull[((size_t)b * TT + t0 + r) * DD + k];
            } else {
                x = src[((size_t)b * TT + t0 + r) * DD + (k - DD)];
            }
            xT[r][c] = x;
        }
        __syncthreads();
#pragma unroll
        for (int kk = 0; kk < 32; kk++) {
            float4 w4 = *(const float4*)&wT[kk][tx * 4];
#pragma unroll
            for (int r4 = 0; r4 < 8; r4++) {
                float x = xT[ty + r4 * 4][kk];
                acc[r4].x += x * w4.x; acc[r4].y += x * w4.y;
                acc[r4].z += x * w4.z; acc[r4].w += x * w4.w;
            }
        }
    }
#pragma unroll
    for (int r4 = 0; r4 < 8; r4++) {
        const int t = t0 + ty + r4 * 4;
        float4 o;
        o.x = tanhf(acc[r4].x); o.y = tanhf(acc[r4].y);
        o.z = tanhf(acc[r4].z); o.w = tanhf(acc[r4].w);
        *(float4*)(attn + ((size_t)b * TT + t) * DD + tx * 4) = o;
    }
}

// ---------------------------------------------------------------------------
extern "C" void kernel_launch(void* const* d_in, const int* in_sizes, int n_in,
                              void* d_out, int out_size, void* d_ws, size_t ws_size,
                              hipStream_t stream)
{
    const float* src  = (const float*)d_in[0];   // [B,T,D]
    const float* mem  = (const float*)d_in[1];   // [B,S,D]
    const float* Wout = (const float*)d_in[2];   // [2D,D]
    const int*   lens = (const int*)d_in[3];     // [B]

    float* out    = (float*)d_out;
    float* attn   = out;                               // [B,T,D]
    float* alignb = out + (size_t)BN * TT * DD;        // [B,T,S] scratch -> final

    unsigned int* rowmaxU = (unsigned int*)d_ws;                       // 64 KB
    float* segsum = (float*)(rowmaxU + (size_t)BN * TT);               // 8 MB
    unsigned short* mhi = (unsigned short*)(segsum + (size_t)BN * NSEG * SS); // 8 MB
    unsigned short* shi   = mhi + (size_t)BN * SS * DD;                // 8 MB (dead after k1)
    unsigned short* slo   = shi + (size_t)BN * TT * DD;                // 8 MB (dead after k1)
    unsigned short* mhirm = slo + (size_t)BN * TT * DD;                // 8 MB (dead after k1)
    float* cfull = (float*)shi;   // 16 MB, aliases k1-only fp16 buffers

    kprep<<<dim3(BN * TT * DD / (256 * 8), 3), 256, 0, stream>>>(
        src, mem, shi, slo, mhirm, mhi, rowmaxU);
    k1_mfma<<<dim3(SS / 128, TT / 128, BN), 256, 0, stream>>>(
        shi, slo, mhirm, lens, alignb, rowmaxU);
    k3_segsum<<<dim3(SS / 1024, NSEG, BN), 256, 0, stream>>>(alignb, rowmaxU, lens, segsum);
    k4_prefix<<<dim3(SS / 256, BN), 256, 0, stream>>>(segsum);
    k5_scan<<<dim3(NSEG, BN), 256, 0, stream>>>(alignb, rowmaxU, segsum, lens);
    k6_context<<<dim3(TT / 32, BN), 256, 0, stream>>>(alignb, mhi, lens, cfull);
    k7_out<<<dim3(TT / 32, BN), 256, 0, stream>>>(cfull, src, Wout, attn);
}